// Round 2
// baseline (1079.892 us; speedup 1.0000x reference)
//
#include <hip/hip_runtime.h>
#include <hip/hip_bf16.h>

typedef __bf16 bf16x8 __attribute__((ext_vector_type(8)));
typedef float f32x4 __attribute__((ext_vector_type(4)));
typedef unsigned short u16;
typedef unsigned int u32;

#define M_ROWS 8192
#define DMODEL 2048
#define DFFN   8192

__device__ __forceinline__ u16 f2bf(float f) {
  u32 u = __float_as_uint(f);
  u32 r = u + 0x7fffu + ((u >> 16) & 1u);
  return (u16)(r >> 16);
}

__device__ __forceinline__ void async16(const void* g, void* l) {
  __builtin_amdgcn_global_load_lds((const __attribute__((address_space(1))) u32*)g,
                                   (__attribute__((address_space(3))) u32*)l, 16, 0, 0);
}

// ---------------- fp32 -> bf16 elementwise (x) ----------------
__global__ void conv_bf16x4(const float* __restrict__ in, u16* __restrict__ out, int n4) {
  int i = blockIdx.x * blockDim.x + threadIdx.x;
  if (i >= n4) return;
  float4 v = reinterpret_cast<const float4*>(in)[i];
  ushort4 o;
  o.x = f2bf(v.x); o.y = f2bf(v.y); o.z = f2bf(v.z); o.w = f2bf(v.w);
  reinterpret_cast<ushort4*>(out)[i] = o;
}

// ------------- transpose + convert (weights -> B^T bf16) -------------
// in: [R][C] fp32.  out row v(c) (length R bf16) = column c of in.
// ILV=1: v = (c>>4)*32 + sel*16 + (c&15)  (16-col interleave of gate/up)
template <int ILV>
__global__ void transpose_conv(const float* __restrict__ in, u16* __restrict__ out,
                               int R, int C, int sel) {
  __shared__ float tl[64][65];
  const int t = threadIdx.x;
  const int r0 = blockIdx.y * 64, c0 = blockIdx.x * 64;
#pragma unroll
  for (int pr = 0; pr < 4; ++pr) {
    int rl = pr * 16 + (t >> 4);
    int cl = (t & 15) * 4;
    float4 v = *reinterpret_cast<const float4*>(&in[(size_t)(r0 + rl) * C + c0 + cl]);
    tl[rl][cl] = v.x; tl[rl][cl + 1] = v.y; tl[rl][cl + 2] = v.z; tl[rl][cl + 3] = v.w;
  }
  __syncthreads();
#pragma unroll
  for (int pc = 0; pc < 4; ++pc) {
    int cl = pc * 16 + (t >> 4);
    int rl = (t & 15) * 4;
    ushort4 o;
    o.x = f2bf(tl[rl + 0][cl]); o.y = f2bf(tl[rl + 1][cl]);
    o.z = f2bf(tl[rl + 2][cl]); o.w = f2bf(tl[rl + 3][cl]);
    int c = c0 + cl;
    int v = ILV ? ((c >> 4) * 32 + sel * 16 + (c & 15)) : c;
    *reinterpret_cast<ushort4*>(&out[(size_t)v * R + r0 + rl]) = o;
  }
}

// ---------------- top-k indices -> bitmask ----------------
// Robust to the harness delivering indices as int32 OR int64:
// int64 little-endian => word[1] (high half of idx[0]) == 0;
// int32 => word[1] = idx[1] >= 1 (sorted unique, idx[1] > idx[0] >= 0).
__global__ void build_mask(const u32* __restrict__ idxw, u32* __restrict__ mask, int total) {
  int i = blockIdx.x * blockDim.x + threadIdx.x;
  if (i >= total) return;
  bool is64 = (idxw[1] == 0u);
  int m = i >> 9;  // 512 indices per row
  int j = is64 ? (int)idxw[2 * i] : (int)idxw[i];
  atomicOr(&mask[(size_t)m * 256 + (j >> 5)], 1u << (j & 31));
}

// ---------------- GEMM core: C = A @ B^T ----------------
// A: [.][K] bf16 row-major, B: [.][K] bf16 row-major (i.e. B^T layout).
// 128x128 tile, BK=64, 4 waves (2x2), each wave 64x64 via 4x4 16x16x32 MFMA frags.
// 1D grid, remapped: bijective XCD chunking + GROUP_M=8 band order (8 consecutive
// ids share one B panel, stepping y) for L2 locality.
// MODE 0: virtual N=2*DFFN interleaved gate/up -> Z = mask * silu(g) * u, bf16 [.][DFFN]
// MODE 1: plain fp32 store to out [.][DMODEL]
template <int MODE, int NBX, int NBY>
__global__ __launch_bounds__(256, 3)
void gemm_bt(const u16* __restrict__ A, const u16* __restrict__ B, int K,
             void* __restrict__ outp, const u32* __restrict__ mask) {
  // --- block remap (all uniform/scalar) ---
  constexpr int T = NBX * NBY;
  constexpr int CHUNK = T / 8;      // T % 8 == 0 for our launches
  constexpr int GM = 8;             // NBY % 8 == 0
  constexpr int BAND = GM * NBX;
  int id = blockIdx.x;
  id = (id & 7) * CHUNK + (id >> 3);          // contiguous chunk per XCD
  const int bgrp = id / BAND, brem = id % BAND;
  const int by = bgrp * GM + (brem % GM);     // y fast within group of 8
  const int bx = brem / GM;                   // x slow -> 8 ids share B panel

  __shared__ __align__(16) u16 As[128 * 64];
  __shared__ __align__(16) u16 Bs[128 * 64];
  const int tid = threadIdx.x;
  const int lane = tid & 63;
  const int wave = tid >> 6;
  const int wr = wave >> 1, wc = wave & 1;
  const int lrow = lane & 15;          // fragment row (A) / col (B)
  const int lkb = (lane >> 4) << 4;    // byte offset of this lane's 8 k-elems

  f32x4 acc[4][4];
#pragma unroll
  for (int m = 0; m < 4; ++m)
#pragma unroll
    for (int n = 0; n < 4; ++n) acc[m][n] = (f32x4){0.f, 0.f, 0.f, 0.f};

  const size_t ldab = (size_t)K * 2;  // row stride in bytes
  const char* Abase = (const char*)A + (size_t)by * 128 * ldab;
  const char* Bbase = (const char*)B + (size_t)bx * 128 * ldab;

  // staging geometry: 16KB tile = 4 issues x (256 thr x 16B). LDS dest linear,
  // global source pre-swizzled with the same involution the ds_read applies
  // (both-sides-or-neither, rule #21).
  int srow[4], scb[4];
#pragma unroll
  for (int i = 0; i < 4; ++i) {
    int X = i * 4096 + tid * 16;
    srow[i] = X >> 7;
    scb[i] = (X & 127) ^ ((srow[i] & 7) << 4);
  }

  for (int kt = 0; kt < K; kt += 64) {
#pragma unroll
    for (int i = 0; i < 4; ++i) {
      async16(Abase + (size_t)srow[i] * ldab + (size_t)kt * 2 + scb[i],
              (char*)As + i * 4096 + wave * 1024);
      async16(Bbase + (size_t)srow[i] * ldab + (size_t)kt * 2 + scb[i],
              (char*)Bs + i * 4096 + wave * 1024);
    }
    __syncthreads();   // compiler drains vmcnt before s_barrier -> LDS valid
#pragma unroll
    for (int ks = 0; ks < 2; ++ks) {
      bf16x8 af[4], bfr[4];
#pragma unroll
      for (int m = 0; m < 4; ++m) {
        int row = wr * 64 + m * 16 + lrow;
        int off = row * 128 + ((ks * 64 + lkb) ^ ((row & 7) << 4));
        af[m] = *reinterpret_cast<const bf16x8*>((const char*)As + off);
      }
#pragma unroll
      for (int n = 0; n < 4; ++n) {
        int row = wc * 64 + n * 16 + lrow;
        int off = row * 128 + ((ks * 64 + lkb) ^ ((row & 7) << 4));
        bfr[n] = *reinterpret_cast<const bf16x8*>((const char*)Bs + off);
      }
#pragma unroll
      for (int m = 0; m < 4; ++m)
#pragma unroll
        for (int n = 0; n < 4; ++n)
          acc[m][n] = __builtin_amdgcn_mfma_f32_16x16x32_bf16(af[m], bfr[n], acc[m][n], 0, 0, 0);
    }
    __syncthreads();
  }

  if (MODE == 0) {
    // virtual cols: pairs (gate,up) of 16; real 16-col group = bx*4 + wc*2 + p
    u16* Z = (u16*)outp;
    const int colw = bx * 2 + wc;  // mask word index (col>>5)
#pragma unroll
    for (int m = 0; m < 4; ++m) {
#pragma unroll
      for (int j = 0; j < 4; ++j) {
        int gr = by * 128 + wr * 64 + m * 16 + ((lane >> 4) << 2) + j;
        u32 w = mask[(size_t)gr * 256 + colw];
#pragma unroll
        for (int p = 0; p < 2; ++p) {
          float g = acc[m][2 * p][j];
          float u = acc[m][2 * p + 1][j];
          float z = 0.f;
          if ((w >> (p * 16 + lrow)) & 1u) z = g * u / (1.f + __expf(-g));
          int gc = (bx * 4 + wc * 2 + p) * 16 + lrow;
          Z[(size_t)gr * DFFN + gc] = f2bf(z);
        }
      }
    }
  } else {
    float* O = (float*)outp;
#pragma unroll
    for (int m = 0; m < 4; ++m) {
#pragma unroll
      for (int j = 0; j < 4; ++j) {
        int gr = by * 128 + wr * 64 + m * 16 + ((lane >> 4) << 2) + j;
#pragma unroll
        for (int n = 0; n < 4; ++n) {
          int gc = bx * 128 + wc * 64 + n * 16 + lrow;
          O[(size_t)gr * DMODEL + gc] = acc[m][n][j];
        }
      }
    }
  }
}

extern "C" void kernel_launch(void* const* d_in, const int* in_sizes, int n_in,
                              void* d_out, int out_size, void* d_ws, size_t ws_size,
                              hipStream_t stream) {
  (void)in_sizes; (void)n_in; (void)out_size; (void)ws_size;
  const float* x   = (const float*)d_in[0];
  const u32*   ix  = (const u32*)d_in[1];
  const float* wg  = (const float*)d_in[2];
  const float* wu  = (const float*)d_in[3];
  const float* wd  = (const float*)d_in[4];

  // workspace layout (232 MB):
  //   [0,32)    xb   : x bf16 [8192][2048]   -- dead after GEMM1; wdT aliases it
  //   [32,96)   wcomb: interleaved WgT/WuT bf16 [16384][2048]
  //   [96,224)  Zb   : Z bf16 [8192][8192]
  //   [224,232) mask : bitmask [8192][256] u32
  char* ws = (char*)d_ws;
  u16* xb    = (u16*)(ws);
  u16* wcomb = (u16*)(ws + (size_t)32 * 1048576);
  u16* Zb    = (u16*)(ws + (size_t)96 * 1048576);
  u32* mask  = (u32*)(ws + (size_t)224 * 1048576);
  u16* wdT   = (u16*)(ws);  // aliases xb, used only after GEMM1

  // 1. convert x to bf16
  conv_bf16x4<<<(M_ROWS * DMODEL / 4 + 255) / 256, 256, 0, stream>>>(x, xb, M_ROWS * DMODEL / 4);
  // 2. transpose+interleave gate/up weights
  dim3 tgrid(DFFN / 64, DMODEL / 64);
  transpose_conv<1><<<tgrid, 256, 0, stream>>>(wg, wcomb, DMODEL, DFFN, 0);
  transpose_conv<1><<<tgrid, 256, 0, stream>>>(wu, wcomb, DMODEL, DFFN, 1);
  // 3. build bitmask from top-k indices
  hipMemsetAsync(mask, 0, (size_t)M_ROWS * 256 * 4, stream);
  build_mask<<<(M_ROWS * 512 + 255) / 256, 256, 0, stream>>>(ix, mask, M_ROWS * 512);
  // 4. fused GEMM1: Z = mask * silu(x@Wg) * (x@Wu)   (virtual N = 16384)
  gemm_bt<0, 2 * DFFN / 128, M_ROWS / 128>
      <<<(2 * DFFN / 128) * (M_ROWS / 128), 256, 0, stream>>>(xb, wcomb, DMODEL, Zb, mask);
  // 5. transpose down-proj weights (into xb's region, now dead)
  dim3 dgrid(DMODEL / 64, DFFN / 64);
  transpose_conv<0><<<dgrid, 256, 0, stream>>>(wd, wdT, DFFN, DMODEL, 0);
  // 6. GEMM2: Y = Z @ Wd
  gemm_bt<1, DMODEL / 128, M_ROWS / 128>
      <<<(DMODEL / 128) * (M_ROWS / 128), 256, 0, stream>>>(Zb, wdT, DFFN, d_out, nullptr);
}